// Round 12
// baseline (150.665 us; speedup 1.0000x reference)
//
#include <hip/hip_runtime.h>

// DecorrelationNormalization (group whitening), x: [32,64,64,256] f32 NHWC.
// N = 131072 rows of 256 channels (1 KB each), 16 groups of m=16.
// R12: k1 occupancy, retried now that the per-wave epilogue is gone (R9's
// failure mode). NW=4096 waves in 1024 blocks -> 4 blocks/CU = 4 waves/SIMD
// (was 2), __launch_bounds__(256,4) caps VGPR at 128 (need ~106, no spill),
// prefetch 2-deep (TLP supplies MLP). Everything else = R11 (epilogue-free
// k1 w/ global raw-acc store, parallel reduce, 16-block chol, k3 unchanged).

#define NROWS   131072
#define DENOMF  131071.0f
#define EPSV    0.001f

// ws float offsets
#define OFF_INV    0        // [16][256] inv_sqrt row-major
#define OFF_BIAS   4096     // [16][16]
#define OFF_RED2   4352     // [16][4352] slice-reduced raw accumulators
#define OFF_PART2  73984    // [NW][4352] per-wave raw accumulators
#define ACCN       4352     // 68 accs x 64 lanes
#define NSLICE2    16

// DPP quad_perm: xor1=[1,0,3,2]=0xB1, xor2=[2,3,0,1]=0x4E, xor3=[3,2,1,0]=0x1B.
template <int CTRL>
__device__ __forceinline__ float dpp1(float v) {
    int iv = __builtin_bit_cast(int, v);
    int r = __builtin_amdgcn_update_dpp(iv, iv, CTRL, 0xF, 0xF, false);
    return __builtin_bit_cast(float, r);
}
template <int CTRL>
__device__ __forceinline__ float4 dpp4(float4 v) {
    float4 r;
    r.x = dpp1<CTRL>(v.x);
    r.y = dpp1<CTRL>(v.y);
    r.z = dpp1<CTRL>(v.z);
    r.w = dpp1<CTRL>(v.w);
    return r;
}

#define FMA4(A, V, S) \
    A.x = fmaf(V.x, S, A.x); A.y = fmaf(V.y, S, A.y); \
    A.z = fmaf(V.z, S, A.z); A.w = fmaf(V.w, S, A.w)

#define DOT4(O, A, V) \
    O = fmaf(A.x, V.x, O); O = fmaf(A.y, V.y, O); \
    O = fmaf(A.z, V.z, O); O = fmaf(A.w, V.w, O)

// ---------------- Phase 1: stats (epilogue-free) ----------------
// grid (NW/4) x 256 thr, 4 blocks/CU. Wave W owns rows [W*RW, (W+1)*RW),
// 1 row/iter, 2-deep branch-free prefetch. Lane l: channels [4l,4l+4),
// quad q=l&3, group g=l>>2. Acc A<i><m>.c = sum v0[i]*vm[c].
// Store: part[W][k][lane], k = i*16+m*4+c (64 rect) / 64+c (channel sums).
__global__ __launch_bounds__(256, 4) void k1_stats(const float* __restrict__ x,
                                                   float* __restrict__ ws, int NW) {
    const int tid = threadIdx.x;
    const int lane = tid & 63, wv = tid >> 6;
    const int W = blockIdx.x * 4 + wv;
    const int RW = NROWS / NW;             // rows per wave
    const float4* xp = reinterpret_cast<const float4*>(x) + (size_t)W * RW * 64 + lane;

    float4 A00 = {0,0,0,0}, A01 = {0,0,0,0}, A02 = {0,0,0,0}, A03 = {0,0,0,0};
    float4 A10 = {0,0,0,0}, A11 = {0,0,0,0}, A12 = {0,0,0,0}, A13 = {0,0,0,0};
    float4 A20 = {0,0,0,0}, A21 = {0,0,0,0}, A22 = {0,0,0,0}, A23 = {0,0,0,0};
    float4 A30 = {0,0,0,0}, A31 = {0,0,0,0}, A32 = {0,0,0,0}, A33 = {0,0,0,0};
    float4 s4v = {0,0,0,0};

#define PROC1(V)                                                              \
    {                                                                         \
        float4 v0 = (V);                                                      \
        float4 v1 = dpp4<0xB1>(v0);                                           \
        float4 v2 = dpp4<0x4E>(v0);                                           \
        float4 v3 = dpp4<0x1B>(v0);                                           \
        s4v.x += v0.x; s4v.y += v0.y; s4v.z += v0.z; s4v.w += v0.w;           \
        FMA4(A00, v0, v0.x); FMA4(A01, v1, v0.x); FMA4(A02, v2, v0.x); FMA4(A03, v3, v0.x); \
        FMA4(A10, v0, v0.y); FMA4(A11, v1, v0.y); FMA4(A12, v2, v0.y); FMA4(A13, v3, v0.y); \
        FMA4(A20, v0, v0.z); FMA4(A21, v1, v0.z); FMA4(A22, v2, v0.z); FMA4(A23, v3, v0.z); \
        FMA4(A30, v0, v0.w); FMA4(A31, v1, v0.w); FMA4(A32, v2, v0.w); FMA4(A33, v3, v0.w); \
    }

    float4 c0 = xp[0], c1 = xp[64];
    for (int i = 0; i < RW; ++i) {
        const int ip = (i + 2 < RW) ? (i + 2) : (RW - 1);
        float4 nx = xp[(size_t)ip * 64];          // always issued
        PROC1(c0);
        c0 = c1; c1 = nx;
    }
#undef PROC1

    // 68 coalesced stores; no LDS, no atomics, no syncthreads.
    float* pw = ws + OFF_PART2 + (size_t)W * ACCN;
#define STQ(KB, A) \
    pw[(KB + 0) * 64 + lane] = A.x; pw[(KB + 1) * 64 + lane] = A.y; \
    pw[(KB + 2) * 64 + lane] = A.z; pw[(KB + 3) * 64 + lane] = A.w
    STQ( 0, A00); STQ( 4, A01); STQ( 8, A02); STQ(12, A03);
    STQ(16, A10); STQ(20, A11); STQ(24, A12); STQ(28, A13);
    STQ(32, A20); STQ(36, A21); STQ(40, A22); STQ(44, A23);
    STQ(48, A30); STQ(52, A31); STQ(56, A32); STQ(60, A33);
    STQ(64, s4v);
#undef STQ
}

// ---------------- Phase 2a: parallel raw-acc reduction ----------------
// grid (17, 16) x 256. Thread (t,y): red[y][t] = sum over NW/16 waves.
__global__ __launch_bounds__(256, 4) void k2_reduce(float* __restrict__ ws, int NW) {
    const int t = blockIdx.x * 256 + threadIdx.x;
    if (t >= ACCN) return;
    const int per = NW / NSLICE2;
    const float* p = ws + OFF_PART2 + (size_t)(blockIdx.y * per) * ACCN + t;
    float sum = 0.0f;
#pragma unroll 8
    for (int b = 0; b < per; ++b) sum += p[(size_t)b * ACCN];
    ws[OFF_RED2 + (size_t)blockIdx.y * ACCN + t] = sum;
}

// ---------------- Phase 2b: gather rect -> cov -> cholesky -> inverse ----------------
// 16 blocks (one group) x 64 threads. rect(ii,kk) picked from raw layout:
// lane_pos = 4g + (ii>>2), k_idx = (ii&3)*16 + ((ii>>2)^(kk>>2))*4 + (kk&3).
__global__ void k2_chol(float* __restrict__ ws, int NW) {
    __shared__ float cs[16];
    const int g = blockIdx.x, tid = threadIdx.x;
    const float* red = ws + OFF_RED2;

    if (tid < 16) {
        const int lp = 4 * g + (tid >> 2);
        const int kx = 64 + (tid & 3);
        float s = 0.0f;
#pragma unroll
        for (int y = 0; y < NSLICE2; ++y) s += red[(size_t)y * ACCN + kx * 64 + lp];
        cs[tid] = s;
    }
    __syncthreads();

    const int ii = tid & 15;
    const int q = ii >> 2, i = ii & 3;
    const int lp = 4 * g + q;
    const float inv_denom = 1.0f / DENOMF;
    const float mu_l = cs[ii] * (1.0f / (float)NROWS);

    float arow[16];
#pragma unroll
    for (int kk = 0; kk < 16; ++kk) {
        const int kx = i * 16 + (q ^ (kk >> 2)) * 4 + (kk & 3);
        float rect = 0.0f;
#pragma unroll
        for (int y = 0; y < NSLICE2; ++y) rect += red[(size_t)y * ACCN + kx * 64 + lp];
        float mu_k = __shfl(mu_l, kk, 64);
        float cv = (rect - (float)NROWS * mu_l * mu_k) * inv_denom;  // /(N-1)
        cv = cv * (1.0f - EPSV) + ((kk == ii) ? EPSV : 0.0f);        // shrink
        arow[kk] = cv * inv_denom;                                   // faithful 2nd /(N-1)
    }

    float lrow[16];
#pragma unroll
    for (int j = 0; j < 16; ++j) {
        float diag = __shfl(arow[j], j, 64);
        float ljj  = sqrtf(diag);
        float lij  = (ii == j) ? ljj : arow[j] / ljj;
        lrow[j] = lij;
#pragma unroll
        for (int k = j + 1; k < 16; ++k) {
            float lkj = __shfl(lij, k, 64);
            arow[k] = fmaf(-lij, lkj, arow[k]);
        }
    }

    float xcol[16];
#pragma unroll
    for (int i2 = 0; i2 < 16; ++i2) {
        float ssum = (ii == i2) ? 1.0f : 0.0f;
#pragma unroll
        for (int k = 0; k < 16; ++k) {
            if (k < i2) {
                float Lik = __shfl(lrow[k], i2, 64);
                ssum = fmaf(-Lik, xcol[k], ssum);
            }
        }
        float Lii = __shfl(lrow[i2], i2, 64);
        xcol[i2] = (i2 >= ii) ? ssum / Lii : 0.0f;
    }

    float* invg = ws + OFF_INV + g * 256;
#pragma unroll
    for (int i2 = 0; i2 < 16; ++i2) {
        if (tid < 16) invg[i2 * 16 + tid] = xcol[i2];
        float bi = xcol[i2] * mu_l;
        bi += __shfl_xor(bi, 1, 64);
        bi += __shfl_xor(bi, 2, 64);
        bi += __shfl_xor(bi, 4, 64);
        bi += __shfl_xor(bi, 8, 64);
        if (tid == 0) ws[OFF_BIAS + g * 16 + i2] = bi;
    }
}

// ---------------- Phase 3: apply out = inv*x - bias ----------------
// grid 1024 x 256 thr (4 waves), branch-free 1-deep prefetch, DPP exchange.
__global__ __launch_bounds__(256, 4) void k3_apply(const float* __restrict__ x,
                                                   const float* __restrict__ ws,
                                                   float* __restrict__ out) {
    const int tid = threadIdx.x, lane = tid & 63, wv = tid >> 6;
    const int q = lane & 3, g = lane >> 2;

    const float* invg = ws + OFF_INV + g * 256;
#define LOADIR(R, M) \
    *reinterpret_cast<const float4*>(invg + (4 * q + (R)) * 16 + 4 * (q ^ (M)))
    float4 ir00 = LOADIR(0, 0), ir01 = LOADIR(0, 1), ir02 = LOADIR(0, 2), ir03 = LOADIR(0, 3);
    float4 ir10 = LOADIR(1, 0), ir11 = LOADIR(1, 1), ir12 = LOADIR(1, 2), ir13 = LOADIR(1, 3);
    float4 ir20 = LOADIR(2, 0), ir21 = LOADIR(2, 1), ir22 = LOADIR(2, 2), ir23 = LOADIR(2, 3);
    float4 ir30 = LOADIR(3, 0), ir31 = LOADIR(3, 1), ir32 = LOADIR(3, 2), ir33 = LOADIR(3, 3);
#undef LOADIR
    float4 b4 = *reinterpret_cast<const float4*>(ws + OFF_BIAS + g * 16 + 4 * q);

    const int rpb   = NROWS / gridDim.x;   // 128
    const int iters = rpb / 4;             // 32
    const size_t rowbase = (size_t)blockIdx.x * rpb;
    const float4* xp = reinterpret_cast<const float4*>(x) + rowbase * 64 + lane;
    float4*       op = reinterpret_cast<float4*>(out)     + rowbase * 64 + lane;

    float4 cur = xp[(size_t)wv * 64];
    for (int i = 0; i < iters; ++i) {
        const int ip = (i + 1 < iters) ? (i + 1) : (iters - 1);
        float4 nxt = xp[(size_t)(ip * 4 + wv) * 64];

        float4 v0 = cur;
        float4 v1 = dpp4<0xB1>(cur);
        float4 v2 = dpp4<0x4E>(cur);
        float4 v3 = dpp4<0x1B>(cur);

        float o0 = -b4.x, o1 = -b4.y, o2 = -b4.z, o3 = -b4.w;
        DOT4(o0, ir00, v0); DOT4(o0, ir01, v1); DOT4(o0, ir02, v2); DOT4(o0, ir03, v3);
        DOT4(o1, ir10, v0); DOT4(o1, ir11, v1); DOT4(o1, ir12, v2); DOT4(o1, ir13, v3);
        DOT4(o2, ir20, v0); DOT4(o2, ir21, v1); DOT4(o2, ir22, v2); DOT4(o2, ir23, v3);
        DOT4(o3, ir30, v0); DOT4(o3, ir31, v1); DOT4(o3, ir32, v2); DOT4(o3, ir33, v3);

        op[(size_t)(i * 4 + wv) * 64] = make_float4(o0, o1, o2, o3);
        cur = nxt;
    }
}

extern "C" void kernel_launch(void* const* d_in, const int* in_sizes, int n_in,
                              void* d_out, int out_size, void* d_ws, size_t ws_size,
                              hipStream_t stream) {
    const float* x = (const float*)d_in[0];
    float* out = (float*)d_out;
    float* ws  = (float*)d_ws;

    // wave-count tier by workspace size (4096-tier = 71.6 MB; ws observed 512 MB)
    int NW = 1024;
    if (ws_size >= (size_t)(OFF_PART2 + 4096 * ACCN) * sizeof(float)) NW = 4096;
    else if (ws_size >= (size_t)(OFF_PART2 + 2048 * ACCN) * sizeof(float)) NW = 2048;

    k1_stats<<<NW / 4, 256, 0, stream>>>(x, ws, NW);
    dim3 rg((ACCN + 255) / 256, NSLICE2);
    k2_reduce<<<rg, 256, 0, stream>>>(ws, NW);
    k2_chol<<<16, 64, 0, stream>>>(ws, NW);
    k3_apply<<<1024, 256, 0, stream>>>(x, ws, out);
}

// Round 13
// 132.326 us; speedup vs baseline: 1.1386x; 1.1386x over previous
//
#include <hip/hip_runtime.h>

// DecorrelationNormalization (group whitening), x: [32,64,64,256] f32 NHWC.
// N = 131072 rows of 256 channels (1 KB each), 16 groups of m=16.
// R13: k1 deep load ring. Cross-round data: k1 ~3300 cy/row = cold-HBM
// latency exposed (runs right after the 512MB ws-poison evicts L3; FETCH=66MB
// = half of x cold). Prior prefetch depth never exceeded ~2 rows (~600 cy of
// issue) < 900 cy miss latency. Now: 6-row in-flight ring, 2 rows/iter ->
// lookahead ~1000+ cy. Regs: 68 acc + 24 ring + 16 transients ~ 116 < 128.
// NW=2048 (R11 best-total config). k2/k3 verbatim R11.

#define NROWS   131072
#define DENOMF  131071.0f
#define EPSV    0.001f

// ws float offsets
#define OFF_INV    0        // [16][256] inv_sqrt row-major
#define OFF_BIAS   4096     // [16][16]
#define OFF_RED2   4352     // [16][4352] slice-reduced raw accumulators
#define OFF_PART2  73984    // [NW][4352] per-wave raw accumulators
#define ACCN       4352     // 68 accs x 64 lanes
#define NSLICE2    16

// DPP quad_perm: xor1=[1,0,3,2]=0xB1, xor2=[2,3,0,1]=0x4E, xor3=[3,2,1,0]=0x1B.
template <int CTRL>
__device__ __forceinline__ float dpp1(float v) {
    int iv = __builtin_bit_cast(int, v);
    int r = __builtin_amdgcn_update_dpp(iv, iv, CTRL, 0xF, 0xF, false);
    return __builtin_bit_cast(float, r);
}
template <int CTRL>
__device__ __forceinline__ float4 dpp4(float4 v) {
    float4 r;
    r.x = dpp1<CTRL>(v.x);
    r.y = dpp1<CTRL>(v.y);
    r.z = dpp1<CTRL>(v.z);
    r.w = dpp1<CTRL>(v.w);
    return r;
}

#define FMA4(A, V, S) \
    A.x = fmaf(V.x, S, A.x); A.y = fmaf(V.y, S, A.y); \
    A.z = fmaf(V.z, S, A.z); A.w = fmaf(V.w, S, A.w)

#define DOT4(O, A, V) \
    O = fmaf(A.x, V.x, O); O = fmaf(A.y, V.y, O); \
    O = fmaf(A.z, V.z, O); O = fmaf(A.w, V.w, O)

// ---------------- Phase 1: stats (epilogue-free, 6-row load ring) ----------------
// grid (NW/4) x 256 thr. Wave W owns rows [W*RW, (W+1)*RW), 2 rows/iter,
// ring of 6 rows in flight (lookahead 3 iters ~ 1000+ cy of issue).
// Lane l: channels [4l,4l+4), quad q=l&3, group g=l>>2.
// Acc A<i><m>.c = sum v0[i]*vm[c] -> rect(4q+i, 4(q^m)+c).
// Store: part[W][k][lane], k = i*16+m*4+c (64 rect) / 64+c (channel sums).
__global__ __launch_bounds__(256, 4) void k1_stats(const float* __restrict__ x,
                                                   float* __restrict__ ws, int NW) {
    const int tid = threadIdx.x;
    const int lane = tid & 63, wv = tid >> 6;
    const int W = blockIdx.x * 4 + wv;
    const int RW = NROWS / NW;             // rows per wave (64 at NW=2048)
    const float4* xp = reinterpret_cast<const float4*>(x) + (size_t)W * RW * 64 + lane;

    float4 A00 = {0,0,0,0}, A01 = {0,0,0,0}, A02 = {0,0,0,0}, A03 = {0,0,0,0};
    float4 A10 = {0,0,0,0}, A11 = {0,0,0,0}, A12 = {0,0,0,0}, A13 = {0,0,0,0};
    float4 A20 = {0,0,0,0}, A21 = {0,0,0,0}, A22 = {0,0,0,0}, A23 = {0,0,0,0};
    float4 A30 = {0,0,0,0}, A31 = {0,0,0,0}, A32 = {0,0,0,0}, A33 = {0,0,0,0};
    float4 s4v = {0,0,0,0};

#define PROC1(V)                                                              \
    {                                                                         \
        float4 v0 = (V);                                                      \
        float4 v1 = dpp4<0xB1>(v0);                                           \
        float4 v2 = dpp4<0x4E>(v0);                                           \
        float4 v3 = dpp4<0x1B>(v0);                                           \
        s4v.x += v0.x; s4v.y += v0.y; s4v.z += v0.z; s4v.w += v0.w;           \
        FMA4(A00, v0, v0.x); FMA4(A01, v1, v0.x); FMA4(A02, v2, v0.x); FMA4(A03, v3, v0.x); \
        FMA4(A10, v0, v0.y); FMA4(A11, v1, v0.y); FMA4(A12, v2, v0.y); FMA4(A13, v3, v0.y); \
        FMA4(A20, v0, v0.z); FMA4(A21, v1, v0.z); FMA4(A22, v2, v0.z); FMA4(A23, v3, v0.z); \
        FMA4(A30, v0, v0.w); FMA4(A31, v1, v0.w); FMA4(A32, v2, v0.w); FMA4(A33, v3, v0.w); \
    }

    // 6-row ring prologue
    float4 c0 = xp[0 * 64], c1 = xp[1 * 64], c2 = xp[2 * 64],
           c3 = xp[3 * 64], c4 = xp[4 * 64], c5 = xp[5 * 64];
    for (int i = 0; i < RW; i += 2) {
        const int i6 = (i + 6 < RW) ? (i + 6) : (RW - 1);   // clamp (dup discarded)
        const int i7 = (i + 7 < RW) ? (i + 7) : (RW - 1);
        float4 n0 = xp[(size_t)i6 * 64];                    // always issued
        float4 n1 = xp[(size_t)i7 * 64];
        PROC1(c0);
        PROC1(c1);
        c0 = c2; c1 = c3; c2 = c4; c3 = c5; c4 = n0; c5 = n1;
    }
#undef PROC1

    // 68 coalesced stores; no LDS, no atomics, no syncthreads.
    float* pw = ws + OFF_PART2 + (size_t)W * ACCN;
#define STQ(KB, A) \
    pw[(KB + 0) * 64 + lane] = A.x; pw[(KB + 1) * 64 + lane] = A.y; \
    pw[(KB + 2) * 64 + lane] = A.z; pw[(KB + 3) * 64 + lane] = A.w
    STQ( 0, A00); STQ( 4, A01); STQ( 8, A02); STQ(12, A03);
    STQ(16, A10); STQ(20, A11); STQ(24, A12); STQ(28, A13);
    STQ(32, A20); STQ(36, A21); STQ(40, A22); STQ(44, A23);
    STQ(48, A30); STQ(52, A31); STQ(56, A32); STQ(60, A33);
    STQ(64, s4v);
#undef STQ
}

// ---------------- Phase 2a: parallel raw-acc reduction ----------------
// grid (17, 16) x 256. Thread (t,y): red[y][t] = sum over NW/16 waves.
__global__ __launch_bounds__(256, 4) void k2_reduce(float* __restrict__ ws, int NW) {
    const int t = blockIdx.x * 256 + threadIdx.x;
    if (t >= ACCN) return;
    const int per = NW / NSLICE2;
    const float* p = ws + OFF_PART2 + (size_t)(blockIdx.y * per) * ACCN + t;
    float sum = 0.0f;
#pragma unroll 8
    for (int b = 0; b < per; ++b) sum += p[(size_t)b * ACCN];
    ws[OFF_RED2 + (size_t)blockIdx.y * ACCN + t] = sum;
}

// ---------------- Phase 2b: gather rect -> cov -> cholesky -> inverse ----------------
// 16 blocks (one group) x 64 threads. rect(ii,kk) picked from raw layout:
// lane_pos = 4g + (ii>>2), k_idx = (ii&3)*16 + ((ii>>2)^(kk>>2))*4 + (kk&3).
__global__ void k2_chol(float* __restrict__ ws, int NW) {
    __shared__ float cs[16];
    const int g = blockIdx.x, tid = threadIdx.x;
    const float* red = ws + OFF_RED2;

    if (tid < 16) {
        const int lp = 4 * g + (tid >> 2);
        const int kx = 64 + (tid & 3);
        float s = 0.0f;
#pragma unroll
        for (int y = 0; y < NSLICE2; ++y) s += red[(size_t)y * ACCN + kx * 64 + lp];
        cs[tid] = s;
    }
    __syncthreads();

    const int ii = tid & 15;
    const int q = ii >> 2, i = ii & 3;
    const int lp = 4 * g + q;
    const float inv_denom = 1.0f / DENOMF;
    const float mu_l = cs[ii] * (1.0f / (float)NROWS);

    float arow[16];
#pragma unroll
    for (int kk = 0; kk < 16; ++kk) {
        const int kx = i * 16 + (q ^ (kk >> 2)) * 4 + (kk & 3);
        float rect = 0.0f;
#pragma unroll
        for (int y = 0; y < NSLICE2; ++y) rect += red[(size_t)y * ACCN + kx * 64 + lp];
        float mu_k = __shfl(mu_l, kk, 64);
        float cv = (rect - (float)NROWS * mu_l * mu_k) * inv_denom;  // /(N-1)
        cv = cv * (1.0f - EPSV) + ((kk == ii) ? EPSV : 0.0f);        // shrink
        arow[kk] = cv * inv_denom;                                   // faithful 2nd /(N-1)
    }

    float lrow[16];
#pragma unroll
    for (int j = 0; j < 16; ++j) {
        float diag = __shfl(arow[j], j, 64);
        float ljj  = sqrtf(diag);
        float lij  = (ii == j) ? ljj : arow[j] / ljj;
        lrow[j] = lij;
#pragma unroll
        for (int k = j + 1; k < 16; ++k) {
            float lkj = __shfl(lij, k, 64);
            arow[k] = fmaf(-lij, lkj, arow[k]);
        }
    }

    float xcol[16];
#pragma unroll
    for (int i2 = 0; i2 < 16; ++i2) {
        float ssum = (ii == i2) ? 1.0f : 0.0f;
#pragma unroll
        for (int k = 0; k < 16; ++k) {
            if (k < i2) {
                float Lik = __shfl(lrow[k], i2, 64);
                ssum = fmaf(-Lik, xcol[k], ssum);
            }
        }
        float Lii = __shfl(lrow[i2], i2, 64);
        xcol[i2] = (i2 >= ii) ? ssum / Lii : 0.0f;
    }

    float* invg = ws + OFF_INV + g * 256;
#pragma unroll
    for (int i2 = 0; i2 < 16; ++i2) {
        if (tid < 16) invg[i2 * 16 + tid] = xcol[i2];
        float bi = xcol[i2] * mu_l;
        bi += __shfl_xor(bi, 1, 64);
        bi += __shfl_xor(bi, 2, 64);
        bi += __shfl_xor(bi, 4, 64);
        bi += __shfl_xor(bi, 8, 64);
        if (tid == 0) ws[OFF_BIAS + g * 16 + i2] = bi;
    }
}

// ---------------- Phase 3: apply out = inv*x - bias ----------------
// grid 1024 x 256 thr (4 waves), branch-free 1-deep prefetch, DPP exchange.
__global__ __launch_bounds__(256, 4) void k3_apply(const float* __restrict__ x,
                                                   const float* __restrict__ ws,
                                                   float* __restrict__ out) {
    const int tid = threadIdx.x, lane = tid & 63, wv = tid >> 6;
    const int q = lane & 3, g = lane >> 2;

    const float* invg = ws + OFF_INV + g * 256;
#define LOADIR(R, M) \
    *reinterpret_cast<const float4*>(invg + (4 * q + (R)) * 16 + 4 * (q ^ (M)))
    float4 ir00 = LOADIR(0, 0), ir01 = LOADIR(0, 1), ir02 = LOADIR(0, 2), ir03 = LOADIR(0, 3);
    float4 ir10 = LOADIR(1, 0), ir11 = LOADIR(1, 1), ir12 = LOADIR(1, 2), ir13 = LOADIR(1, 3);
    float4 ir20 = LOADIR(2, 0), ir21 = LOADIR(2, 1), ir22 = LOADIR(2, 2), ir23 = LOADIR(2, 3);
    float4 ir30 = LOADIR(3, 0), ir31 = LOADIR(3, 1), ir32 = LOADIR(3, 2), ir33 = LOADIR(3, 3);
#undef LOADIR
    float4 b4 = *reinterpret_cast<const float4*>(ws + OFF_BIAS + g * 16 + 4 * q);

    const int rpb   = NROWS / gridDim.x;   // 128
    const int iters = rpb / 4;             // 32
    const size_t rowbase = (size_t)blockIdx.x * rpb;
    const float4* xp = reinterpret_cast<const float4*>(x) + rowbase * 64 + lane;
    float4*       op = reinterpret_cast<float4*>(out)     + rowbase * 64 + lane;

    float4 cur = xp[(size_t)wv * 64];
    for (int i = 0; i < iters; ++i) {
        const int ip = (i + 1 < iters) ? (i + 1) : (iters - 1);
        float4 nxt = xp[(size_t)(ip * 4 + wv) * 64];

        float4 v0 = cur;
        float4 v1 = dpp4<0xB1>(cur);
        float4 v2 = dpp4<0x4E>(cur);
        float4 v3 = dpp4<0x1B>(cur);

        float o0 = -b4.x, o1 = -b4.y, o2 = -b4.z, o3 = -b4.w;
        DOT4(o0, ir00, v0); DOT4(o0, ir01, v1); DOT4(o0, ir02, v2); DOT4(o0, ir03, v3);
        DOT4(o1, ir10, v0); DOT4(o1, ir11, v1); DOT4(o1, ir12, v2); DOT4(o1, ir13, v3);
        DOT4(o2, ir20, v0); DOT4(o2, ir21, v1); DOT4(o2, ir22, v2); DOT4(o2, ir23, v3);
        DOT4(o3, ir30, v0); DOT4(o3, ir31, v1); DOT4(o3, ir32, v2); DOT4(o3, ir33, v3);

        op[(size_t)(i * 4 + wv) * 64] = make_float4(o0, o1, o2, o3);
        cur = nxt;
    }
}

extern "C" void kernel_launch(void* const* d_in, const int* in_sizes, int n_in,
                              void* d_out, int out_size, void* d_ws, size_t ws_size,
                              hipStream_t stream) {
    const float* x = (const float*)d_in[0];
    float* out = (float*)d_out;
    float* ws  = (float*)d_ws;

    // NW=2048 preferred (R11 best-total); tier down by workspace size.
    int NW = 512;
    if (ws_size >= (size_t)(OFF_PART2 + 2048 * ACCN) * sizeof(float)) NW = 2048;
    else if (ws_size >= (size_t)(OFF_PART2 + 1024 * ACCN) * sizeof(float)) NW = 1024;

    k1_stats<<<NW / 4, 256, 0, stream>>>(x, ws, NW);
    dim3 rg((ACCN + 255) / 256, NSLICE2);
    k2_reduce<<<rg, 256, 0, stream>>>(ws, NW);
    k2_chol<<<16, 64, 0, stream>>>(ws, NW);
    k3_apply<<<1024, 256, 0, stream>>>(x, ws, out);
}

// Round 14
// 105.408 us; speedup vs baseline: 1.4294x; 1.2554x over previous
//
#include <hip/hip_runtime.h>

// DecorrelationNormalization (group whitening), x: [32,64,64,256] f32 NHWC.
// N = 131072 rows of 256 channels, 16 groups of m=16.
// R14: k1 rewritten on MFMA. Gram per group = X^T X computed as
// H^T H + H^T L + (H^T L)^T + L^T L with x = hi(bf16,trunc) + lo(bf16,trunc),
// via __builtin_amdgcn_mfma_f32_16x16x32_bf16. A and B fragments are the
// SAME registers (lane: ch = g*16+(lane&15), k: row = (lane>>4)*8+j) -- any
// k-permutation cancels in A^T A; C/D layout is the verified col=lane&15,
// row=(lane>>4)*4+reg. Per (32-row chunk, group): 8 stride-1KB dword loads,
// ~45 bit-op VALU split, 3 MFMA into 12 AGPRs. k3 unchanged (~roofline).

#define NROWS   131072
#define DENOMF  131071.0f
#define EPSV    0.001f

// ws float offsets
#define OFF_INV    0        // [16][256] inv_sqrt row-major
#define OFF_BIAS   4096     // [16][16]
#define OFF_RED3   4352     // [16*832] reduced per-group stats
#define OFF_PART3  17664    // [NW][832] per-wave raw MFMA accs + sums
#define PWN        832      // 12 acc regs * 64 lanes + 64 lane-sums

typedef __attribute__((ext_vector_type(8))) short bf16x8;
typedef __attribute__((ext_vector_type(4))) float f32x4;
typedef __attribute__((ext_vector_type(4))) unsigned int u32x4;

__device__ __forceinline__ unsigned int fbits(float v) {
    return __builtin_bit_cast(unsigned int, v);
}
__device__ __forceinline__ float bfloat(unsigned int u) {
    return __builtin_bit_cast(float, u);
}

struct Row8 { float a, b, c, d, e, f, g, h; };

__device__ __forceinline__ Row8 load8(const float* p) {
    Row8 r;
    r.a = p[0];    r.b = p[256];  r.c = p[512];  r.d = p[768];
    r.e = p[1024]; r.f = p[1280]; r.g = p[1536]; r.h = p[1792];
    return r;
}

// split r into hi (truncated bf16) + lo (bf16 of remainder), packed little-
// endian pairs (elem 2i low half, 2i+1 high half); also accumulate f32 sum.
__device__ __forceinline__ void cvt8(const Row8 r, bf16x8& hv, bf16x8& lv, float& s) {
    s += ((r.a + r.b) + (r.c + r.d)) + ((r.e + r.f) + (r.g + r.h));
    const unsigned int ua = fbits(r.a), ub = fbits(r.b), uc = fbits(r.c), ud = fbits(r.d);
    const unsigned int ue = fbits(r.e), uf = fbits(r.f), ug = fbits(r.g), uh = fbits(r.h);
    u32x4 hp;
    hp.x = (ub & 0xFFFF0000u) | (ua >> 16);
    hp.y = (ud & 0xFFFF0000u) | (uc >> 16);
    hp.z = (uf & 0xFFFF0000u) | (ue >> 16);
    hp.w = (uh & 0xFFFF0000u) | (ug >> 16);
    const float da = r.a - bfloat(ua & 0xFFFF0000u);
    const float db = r.b - bfloat(ub & 0xFFFF0000u);
    const float dc = r.c - bfloat(uc & 0xFFFF0000u);
    const float dd = r.d - bfloat(ud & 0xFFFF0000u);
    const float de = r.e - bfloat(ue & 0xFFFF0000u);
    const float df = r.f - bfloat(uf & 0xFFFF0000u);
    const float dg = r.g - bfloat(ug & 0xFFFF0000u);
    const float dh = r.h - bfloat(uh & 0xFFFF0000u);
    u32x4 lp;
    lp.x = (fbits(db) & 0xFFFF0000u) | (fbits(da) >> 16);
    lp.y = (fbits(dd) & 0xFFFF0000u) | (fbits(dc) >> 16);
    lp.z = (fbits(df) & 0xFFFF0000u) | (fbits(de) >> 16);
    lp.w = (fbits(dh) & 0xFFFF0000u) | (fbits(dg) >> 16);
    hv = __builtin_bit_cast(bf16x8, hp);
    lv = __builtin_bit_cast(bf16x8, lp);
}

// ---------------- Phase 1: MFMA Gram stats ----------------
// grid (NW/4) x 256. Wave W: group g = W&15, strip = W>>4; chunks
// c = strip*UPW + u (u = 0..UPW-1), each chunk = 32 rows.
// Lane: ch = g*16 + (lane&15); rows = c*32 + (lane>>4)*8 + j (j=0..7).
// 2-deep unit lookahead. Stores 13 coalesced values/lane.
__global__ __launch_bounds__(256, 4) void k1_stats(const float* __restrict__ x,
                                                   float* __restrict__ ws, int NW) {
    const int tid = threadIdx.x;
    const int lane = tid & 63, wv = tid >> 6;
    const int W = blockIdx.x * 4 + wv;
    const int UPW = 65536 / NW;            // units (chunks) per wave
    const int g = W & 15, strip = W >> 4;
    const int ch = g * 16 + (lane & 15);
    const size_t row0 = (size_t)strip * UPW * 32 + (size_t)((lane >> 4) * 8);
    const float* p = x + row0 * 256 + ch;

    f32x4 aHH = {0.f, 0.f, 0.f, 0.f};
    f32x4 aHL = {0.f, 0.f, 0.f, 0.f};
    f32x4 aLL = {0.f, 0.f, 0.f, 0.f};
    float s = 0.f;

    Row8 c0 = load8(p);
    Row8 c1 = load8(p + 8192);
    for (int u = 0; u < UPW; ++u) {
        const int up = (u + 2 < UPW) ? (u + 2) : (UPW - 1);
        Row8 nx = load8(p + (size_t)up * 8192);       // always issued
        bf16x8 hv, lv;
        cvt8(c0, hv, lv, s);
        aHH = __builtin_amdgcn_mfma_f32_16x16x32_bf16(hv, hv, aHH, 0, 0, 0);
        aHL = __builtin_amdgcn_mfma_f32_16x16x32_bf16(hv, lv, aHL, 0, 0, 0);
        aLL = __builtin_amdgcn_mfma_f32_16x16x32_bf16(lv, lv, aLL, 0, 0, 0);
        c0 = c1; c1 = nx;
    }

    // layout [13][64]: HH regs 0-3, HL 4-7, LL 8-11, lane-sum 12
    float* pw = ws + OFF_PART3 + (size_t)W * PWN;
    pw[0 * 64 + lane]  = aHH[0]; pw[1 * 64 + lane]  = aHH[1];
    pw[2 * 64 + lane]  = aHH[2]; pw[3 * 64 + lane]  = aHH[3];
    pw[4 * 64 + lane]  = aHL[0]; pw[5 * 64 + lane]  = aHL[1];
    pw[6 * 64 + lane]  = aHL[2]; pw[7 * 64 + lane]  = aHL[3];
    pw[8 * 64 + lane]  = aLL[0]; pw[9 * 64 + lane]  = aLL[1];
    pw[10 * 64 + lane] = aLL[2]; pw[11 * 64 + lane] = aLL[3];
    pw[12 * 64 + lane] = s;
}

// ---------------- Phase 2a: reduce strips ----------------
// red[g*832+k] = sum over strips of part[(g+16*s)*832+k]. 52 blocks x 256.
__global__ __launch_bounds__(256, 2) void k2_reduce(float* __restrict__ ws, int NW) {
    const int t = blockIdx.x * 256 + threadIdx.x;
    if (t >= 16 * PWN) return;
    const int g = t / PWN, k = t % PWN;
    const int S = NW / 16;
    const float* p = ws + OFF_PART3 + (size_t)g * PWN + k;
    float sum = 0.f;
#pragma unroll 8
    for (int i = 0; i < S; ++i) sum += p[(size_t)i * 16 * PWN];
    ws[OFF_RED3 + t] = sum;
}

// ---------------- Phase 2b: gather G -> cov -> cholesky -> inverse ----------------
// 16 blocks x 64. G[i][j] = HH[i][j] + HL[i][j] + HL[j][i] + LL[i][j], where
// T[i][j] = sg[T*256 + (i&3)*64 + ((i>>2)<<4) + j] (C/D layout inverted).
__global__ void k2_chol(float* __restrict__ ws, int NW) {
    __shared__ float sg[PWN];
    const int g = blockIdx.x, tid = threadIdx.x;
    for (int e = tid; e < PWN; e += 64) sg[e] = ws[OFF_RED3 + g * PWN + e];
    __syncthreads();

    const int ii = tid & 15;
    const float inv_denom = 1.0f / DENOMF;
    // channel sums: lane-sum block at 768, lane = (lg<<4)|c
    const float cs_ii = sg[768 + ii] + sg[768 + 16 + ii] +
                        sg[768 + 32 + ii] + sg[768 + 48 + ii];
    const float mu_l = cs_ii * (1.0f / (float)NROWS);

#define GIDX(T, I, J) ((T) * 256 + ((I) & 3) * 64 + ((((I) >> 2)) << 4) + (J))
    float arow[16];
#pragma unroll
    for (int kk = 0; kk < 16; ++kk) {
        float G = sg[GIDX(0, ii, kk)] + sg[GIDX(1, ii, kk)] +
                  sg[GIDX(1, kk, ii)] + sg[GIDX(2, ii, kk)];
        float mu_k = __shfl(mu_l, kk, 64);
        float cv = (G - (float)NROWS * mu_l * mu_k) * inv_denom;    // /(N-1)
        cv = cv * (1.0f - EPSV) + ((kk == ii) ? EPSV : 0.0f);       // shrink
        arow[kk] = cv * inv_denom;                                  // faithful 2nd /(N-1)
    }
#undef GIDX

    float lrow[16];
#pragma unroll
    for (int j = 0; j < 16; ++j) {
        float diag = __shfl(arow[j], j, 64);
        float ljj  = sqrtf(diag);
        float lij  = (ii == j) ? ljj : arow[j] / ljj;
        lrow[j] = lij;
#pragma unroll
        for (int k = j + 1; k < 16; ++k) {
            float lkj = __shfl(lij, k, 64);
            arow[k] = fmaf(-lij, lkj, arow[k]);
        }
    }

    float xcol[16];
#pragma unroll
    for (int i2 = 0; i2 < 16; ++i2) {
        float ssum = (ii == i2) ? 1.0f : 0.0f;
#pragma unroll
        for (int k = 0; k < 16; ++k) {
            if (k < i2) {
                float Lik = __shfl(lrow[k], i2, 64);
                ssum = fmaf(-Lik, xcol[k], ssum);
            }
        }
        float Lii = __shfl(lrow[i2], i2, 64);
        xcol[i2] = (i2 >= ii) ? ssum / Lii : 0.0f;
    }

    float* invg = ws + OFF_INV + g * 256;
#pragma unroll
    for (int i2 = 0; i2 < 16; ++i2) {
        if (tid < 16) invg[i2 * 16 + tid] = xcol[i2];
        float bi = xcol[i2] * mu_l;
        bi += __shfl_xor(bi, 1, 64);
        bi += __shfl_xor(bi, 2, 64);
        bi += __shfl_xor(bi, 4, 64);
        bi += __shfl_xor(bi, 8, 64);
        if (tid == 0) ws[OFF_BIAS + g * 16 + i2] = bi;
    }
}

// ---------------- Phase 3: apply out = inv*x - bias ----------------
// grid 1024 x 256 thr, branch-free 1-deep prefetch, DPP quad_perm exchange.
template <int CTRL>
__device__ __forceinline__ float dpp1(float v) {
    int iv = __builtin_bit_cast(int, v);
    int r = __builtin_amdgcn_update_dpp(iv, iv, CTRL, 0xF, 0xF, false);
    return __builtin_bit_cast(float, r);
}
template <int CTRL>
__device__ __forceinline__ float4 dpp4(float4 v) {
    float4 r;
    r.x = dpp1<CTRL>(v.x);
    r.y = dpp1<CTRL>(v.y);
    r.z = dpp1<CTRL>(v.z);
    r.w = dpp1<CTRL>(v.w);
    return r;
}

#define DOT4(O, A, V) \
    O = fmaf(A.x, V.x, O); O = fmaf(A.y, V.y, O); \
    O = fmaf(A.z, V.z, O); O = fmaf(A.w, V.w, O)

__global__ __launch_bounds__(256, 4) void k3_apply(const float* __restrict__ x,
                                                   const float* __restrict__ ws,
                                                   float* __restrict__ out) {
    const int tid = threadIdx.x, lane = tid & 63, wv = tid >> 6;
    const int q = lane & 3, g = lane >> 2;

    const float* invg = ws + OFF_INV + g * 256;
#define LOADIR(R, M) \
    *reinterpret_cast<const float4*>(invg + (4 * q + (R)) * 16 + 4 * (q ^ (M)))
    float4 ir00 = LOADIR(0, 0), ir01 = LOADIR(0, 1), ir02 = LOADIR(0, 2), ir03 = LOADIR(0, 3);
    float4 ir10 = LOADIR(1, 0), ir11 = LOADIR(1, 1), ir12 = LOADIR(1, 2), ir13 = LOADIR(1, 3);
    float4 ir20 = LOADIR(2, 0), ir21 = LOADIR(2, 1), ir22 = LOADIR(2, 2), ir23 = LOADIR(2, 3);
    float4 ir30 = LOADIR(3, 0), ir31 = LOADIR(3, 1), ir32 = LOADIR(3, 2), ir33 = LOADIR(3, 3);
#undef LOADIR
    float4 b4 = *reinterpret_cast<const float4*>(ws + OFF_BIAS + g * 16 + 4 * q);

    const int rpb   = NROWS / gridDim.x;   // 128
    const int iters = rpb / 4;             // 32
    const size_t rowbase = (size_t)blockIdx.x * rpb;
    const float4* xp = reinterpret_cast<const float4*>(x) + rowbase * 64 + lane;
    float4*       op = reinterpret_cast<float4*>(out)     + rowbase * 64 + lane;

    float4 cur = xp[(size_t)wv * 64];
    for (int i = 0; i < iters; ++i) {
        const int ip = (i + 1 < iters) ? (i + 1) : (iters - 1);
        float4 nxt = xp[(size_t)(ip * 4 + wv) * 64];

        float4 v0 = cur;
        float4 v1 = dpp4<0xB1>(cur);
        float4 v2 = dpp4<0x4E>(cur);
        float4 v3 = dpp4<0x1B>(cur);

        float o0 = -b4.x, o1 = -b4.y, o2 = -b4.z, o3 = -b4.w;
        DOT4(o0, ir00, v0); DOT4(o0, ir01, v1); DOT4(o0, ir02, v2); DOT4(o0, ir03, v3);
        DOT4(o1, ir10, v0); DOT4(o1, ir11, v1); DOT4(o1, ir12, v2); DOT4(o1, ir13, v3);
        DOT4(o2, ir20, v0); DOT4(o2, ir21, v1); DOT4(o2, ir22, v2); DOT4(o2, ir23, v3);
        DOT4(o3, ir30, v0); DOT4(o3, ir31, v1); DOT4(o3, ir32, v2); DOT4(o3, ir33, v3);

        op[(size_t)(i * 4 + wv) * 64] = make_float4(o0, o1, o2, o3);
        cur = nxt;
    }
}

extern "C" void kernel_launch(void* const* d_in, const int* in_sizes, int n_in,
                              void* d_out, int out_size, void* d_ws, size_t ws_size,
                              hipStream_t stream) {
    const float* x = (const float*)d_in[0];
    float* out = (float*)d_out;
    float* ws  = (float*)d_ws;

    // NW waves; partials = NW*832*4 B (13.6 MB at NW=4096). ws observed 512 MB.
    int NW = 1024;
    if (ws_size >= (size_t)(OFF_PART3 + 4096 * PWN) * sizeof(float)) NW = 4096;
    else if (ws_size >= (size_t)(OFF_PART3 + 2048 * PWN) * sizeof(float)) NW = 2048;

    k1_stats<<<NW / 4, 256, 0, stream>>>(x, ws, NW);
    k2_reduce<<<(16 * PWN + 255) / 256, 256, 0, stream>>>(ws, NW);
    k2_chol<<<16, 64, 0, stream>>>(ws, NW);
    k3_apply<<<1024, 256, 0, stream>>>(x, ws, out);
}